// Round 7
// baseline (1250.674 us; speedup 1.0000x reference)
//
#include <hip/hip_runtime.h>

// DrosophilaOpticLobeCircuit: 100-step recurrent sparse circuit.
// R7 = R6 (compressed CSR u16src|bf16w, bf16 r rows) plus:
//  1. Tm1-SOURCE folding: edges from type-0 (clamped) sources have constant
//     contribution; they're segregated into a static suffix per target,
//     evaluated ONCE (k_static) and folded into cF[n][b] = (synS+bias)*g.
//     Step loop processes only the dynamic prefix (-14.3% random gathers).
//  2. 16 lanes per neuron in k_step (two 8-lane groups + xor-8 merge),
//     784k threads -> ~32 waves/CU (was 24): more outstanding misses for
//     the latency/MSHR-bound random gather.

#define BLK 256
#define STEPS 100
#define NBATCH 8
#define PRE2 2             // per-lane slots in k_step (16 lanes: covers deg<=32)
static constexpr float DT_C = 0.1f;

__device__ __forceinline__ unsigned f2bf_rne(float x) {   // fp32 -> bf16 bits (RNE)
    unsigned u = __float_as_uint(x);
    return (u + 0x7FFFu + ((u >> 16) & 1u)) >> 16;
}
__device__ __forceinline__ unsigned pk_bf2(float a, float b) {
    return f2bf_rne(a) | (f2bf_rne(b) << 16);
}

__global__ void k_zero(int* counts, int* countS, int* tm1_pos, int N) {
    int i = blockIdx.x * BLK + threadIdx.x;
    if (i < N) { counts[i] = 0; countS[i] = 0; tm1_pos[i] = -1; }
}

__global__ void k_tm1pos(const int* __restrict__ tm1_idx, int* tm1_pos, int NT) {
    int i = blockIdx.x * BLK + threadIdx.x;
    if (i < NT) tm1_pos[tm1_idx[i]] = i;
}

// total count per target + static (Tm1-source) count + per-edge static flag
__global__ void k_hist(const int* __restrict__ srcI, const int* __restrict__ tgt,
                       const int* __restrict__ type_ids,
                       int* counts, int* countS, unsigned char* __restrict__ flagA,
                       int E) {
    int i = blockIdx.x * BLK + threadIdx.x;
    if (i >= E) return;
    int t = tgt[i];
    atomicAdd(&counts[t], 1);
    unsigned char st = (type_ids[srcI[i]] == 0) ? 1 : 0;
    if (st) atomicAdd(&countS[t], 1);
    flagA[i] = st;
}

__global__ void k_scan1(const int* __restrict__ counts, int* offsets, int* bsum, int N) {
    __shared__ int s[BLK];
    int tx = threadIdx.x;
    int i = blockIdx.x * BLK + tx;
    int v = (i < N) ? counts[i] : 0;
    s[tx] = v; __syncthreads();
    for (int d = 1; d < BLK; d <<= 1) {
        int t = (tx >= d) ? s[tx - d] : 0;
        __syncthreads();
        s[tx] += t;
        __syncthreads();
    }
    if (i < N) offsets[i] = s[tx] - v;
    if (tx == BLK - 1) bsum[blockIdx.x] = s[tx];
}

__global__ void k_scan2(int* bsum, int nb) {
    __shared__ int s[BLK];
    int tx = threadIdx.x;
    int v = (tx < nb) ? bsum[tx] : 0;
    s[tx] = v; __syncthreads();
    for (int d = 1; d < BLK; d <<= 1) {
        int t = (tx >= d) ? s[tx - d] : 0;
        __syncthreads();
        s[tx] += t;
        __syncthreads();
    }
    if (tx < nb) bsum[tx] = s[tx] - v;
}

__global__ void k_scan3(const int* __restrict__ bsum, int* offsets, int N, int E) {
    int i = blockIdx.x * BLK + threadIdx.x;
    if (i < N) {
        offsets[i] += bsum[i >> 8];
    } else if (i == N) {
        offsets[N] = E;
    }
}

// cursors: dynamic writes start at offsets[n], static at dynEnd = off[n+1]-countS
__global__ void k_cursors(const int* __restrict__ offsets, const int* __restrict__ countS,
                          int* cursorD, int* cursorS, int* dynEnd, int N) {
    int i = blockIdx.x * BLK + threadIdx.x;
    if (i >= N) return;
    int o  = offsets[i];
    int dE = offsets[i + 1] - countS[i];
    cursorD[i] = o;
    cursorS[i] = dE;
    dynEnd[i]  = dE;
}

// CSR fill: entry = (bf16(w*scale) << 16) | src_u16 ; static edges go to suffix
__global__ void k_fill(const int* __restrict__ srcI, const int* __restrict__ tgtI,
                       const float* __restrict__ w,
                       const float* __restrict__ se, const float* __restrict__ si,
                       const unsigned char* __restrict__ flagA,
                       int* cursorD, int* cursorS, unsigned* __restrict__ csr, int E) {
    int i = blockIdx.x * BLK + threadIdx.x;
    if (i >= E) return;
    float wv = w[i];
    float sc = wv > 0.f ? se[0] : (wv < 0.f ? si[0] : 1.f);
    float sw = wv * sc;
    unsigned entry = (f2bf_rne(sw) << 16) | (unsigned)srcI[i];
    int t = tgtI[i];
    int pos = flagA[i] ? atomicAdd(&cursorS[t], 1) : atomicAdd(&cursorD[t], 1);
    csr[pos] = entry;
}

// init v_w[N][8] (fp32), r0=r1 bf16 rows, coef = (cA=1-g, cB=g, tm1flag, 0)
__global__ void k_initv(const float* __restrict__ tm1_in, const float* __restrict__ v_init,
                        const float* __restrict__ tau_p,
                        const int* __restrict__ type_ids, const int* __restrict__ tm1_pos,
                        float* __restrict__ v_w, uint4* __restrict__ r0, uint4* __restrict__ r1,
                        float4* __restrict__ coef, int N, int NT) {
    int n = blockIdx.x * BLK + threadIdx.x;
    if (n >= N) return;
    int k = tm1_pos[n];
    float g = DT_C / tau_p[type_ids[n]];
    coef[n] = make_float4(1.f - g, g, (k >= 0) ? 1.f : 0.f, 0.f);
    float vv[NBATCH], rr[NBATCH];
    for (int b = 0; b < NBATCH; ++b) {
        float val = (k >= 0) ? tm1_in[b * NT + k] : v_init[b * N + n];
        vv[b] = val;
        rr[b] = fmaxf(val, 0.f);
    }
    float4* vp = (float4*)(v_w + (size_t)n * 8);
    vp[0] = make_float4(vv[0], vv[1], vv[2], vv[3]);
    vp[1] = make_float4(vv[4], vv[5], vv[6], vv[7]);
    uint4 rq = make_uint4(pk_bf2(rr[0], rr[1]), pk_bf2(rr[2], rr[3]),
                          pk_bf2(rr[4], rr[5]), pk_bf2(rr[6], rr[7]));
    r0[n] = rq;
    r1[n] = rq;
}

// 8-lane-group butterfly transpose-reduce
__device__ __forceinline__ float butterfly8(float4 a0, float4 a1, int sub) {
    int bit0 = sub & 1, bit1 = (sub >> 1) & 1, bit2 = (sub >> 2) & 1;
    float b0 = (bit0 ? a0.y : a0.x) + __shfl_xor(bit0 ? a0.x : a0.y, 1);
    float b1 = (bit0 ? a0.w : a0.z) + __shfl_xor(bit0 ? a0.z : a0.w, 1);
    float b2 = (bit0 ? a1.y : a1.x) + __shfl_xor(bit0 ? a1.x : a1.y, 1);
    float b3 = (bit0 ? a1.w : a1.z) + __shfl_xor(bit0 ? a1.z : a1.w, 1);
    float c0 = (bit1 ? b1 : b0) + __shfl_xor(bit1 ? b0 : b1, 2);
    float c1 = (bit1 ? b3 : b2) + __shfl_xor(bit1 ? b2 : b3, 2);
    return (bit2 ? c1 : c0) + __shfl_xor(bit2 ? c0 : c1, 4);
}

// one-shot static fold: cF[n][b] = (sum_{static edges} w*r_src[b] + bias[n]) * g
__global__ void k_static(const int* __restrict__ offsets, const int* __restrict__ dynEnd,
                         const unsigned* __restrict__ csr, const uint4* __restrict__ r0,
                         const float4* __restrict__ coef, const float* __restrict__ bias,
                         float* __restrict__ cF, int N) {
    int tid = blockIdx.x * BLK + threadIdx.x;
    int n = tid >> 3;
    int sub = threadIdx.x & 7;
    if (n >= N) return;
    float4 cf = coef[n];
    int s = dynEnd[n], e = offsets[n + 1];
    float4 a0 = make_float4(0.f, 0.f, 0.f, 0.f);
    float4 a1 = make_float4(0.f, 0.f, 0.f, 0.f);
    for (int i = s + sub; i < e; i += 8) {
        unsigned ew = csr[i];
        float w = __uint_as_float(ew & 0xFFFF0000u);
        uint4 q = r0[ew & 0xFFFFu];
        a0.x = fmaf(w, __uint_as_float(q.x << 16),          a0.x);
        a0.y = fmaf(w, __uint_as_float(q.x & 0xFFFF0000u),  a0.y);
        a0.z = fmaf(w, __uint_as_float(q.y << 16),          a0.z);
        a0.w = fmaf(w, __uint_as_float(q.y & 0xFFFF0000u),  a0.w);
        a1.x = fmaf(w, __uint_as_float(q.z << 16),          a1.x);
        a1.y = fmaf(w, __uint_as_float(q.z & 0xFFFF0000u),  a1.y);
        a1.z = fmaf(w, __uint_as_float(q.w << 16),          a1.z);
        a1.w = fmaf(w, __uint_as_float(q.w & 0xFFFF0000u),  a1.w);
    }
    float syn = butterfly8(a0, a1, sub);
    cF[(size_t)n * 8 + sub] = (syn + bias[n]) * cf.y;
}

// 16 lanes per neuron (two 8-lane groups, slots idx = s + s16 + 16*j);
// butterfly within group + xor-8 merge across groups; lanes s16<8 store.
__global__ __launch_bounds__(BLK, 8) void k_step(
        const int* __restrict__ offsets, const int* __restrict__ dynEnd,
        const unsigned* __restrict__ csr,
        const float4* __restrict__ coef, const float* __restrict__ cF,
        const uint4* __restrict__ r_prev,
        float* __restrict__ v_w, unsigned short* __restrict__ r_next, int N) {
    int tid = blockIdx.x * BLK + threadIdx.x;
    int n = tid >> 4;
    if (n >= N) return;
    int s16 = threadIdx.x & 15;
    int sub = s16 & 7;
    float4 cf = coef[n];
    if (cf.z != 0.f) return;                 // Tm1 target: clamped, r constant
    int s = offsets[n], e = dynEnd[n];

    // phase A: csr entries (independent predicated loads)
    float wj[PRE2];
    int   sj[PRE2];
    #pragma unroll
    for (int j = 0; j < PRE2; ++j) {
        int idx = s + s16 + 16 * j;
        unsigned ew = (idx < e) ? csr[idx] : 0u;
        wj[j] = __uint_as_float(ew & 0xFFFF0000u);
        sj[j] = (int)(ew & 0xFFFFu);
    }
    // phase B: row gathers (independent predicated loads)
    uint4 q[PRE2];
    #pragma unroll
    for (int j = 0; j < PRE2; ++j) {
        int idx = s + s16 + 16 * j;
        q[j] = (idx < e) ? r_prev[sj[j]] : make_uint4(0u, 0u, 0u, 0u);
    }
    // phase C: unpack + accumulate
    float4 a0 = make_float4(0.f, 0.f, 0.f, 0.f);
    float4 a1 = make_float4(0.f, 0.f, 0.f, 0.f);
    #pragma unroll
    for (int j = 0; j < PRE2; ++j) {
        float w = wj[j];
        a0.x = fmaf(w, __uint_as_float(q[j].x << 16),          a0.x);
        a0.y = fmaf(w, __uint_as_float(q[j].x & 0xFFFF0000u),  a0.y);
        a0.z = fmaf(w, __uint_as_float(q[j].y << 16),          a0.z);
        a0.w = fmaf(w, __uint_as_float(q[j].y & 0xFFFF0000u),  a0.w);
        a1.x = fmaf(w, __uint_as_float(q[j].z << 16),          a1.x);
        a1.y = fmaf(w, __uint_as_float(q[j].z & 0xFFFF0000u),  a1.y);
        a1.z = fmaf(w, __uint_as_float(q[j].w << 16),          a1.z);
        a1.w = fmaf(w, __uint_as_float(q[j].w & 0xFFFF0000u),  a1.w);
    }
    // tail: dynamic degree > 16*PRE2
    for (int i = s + s16 + 16 * PRE2; i < e; i += 16) {
        unsigned ew = csr[i];
        float w = __uint_as_float(ew & 0xFFFF0000u);
        uint4 qq = r_prev[ew & 0xFFFFu];
        a0.x = fmaf(w, __uint_as_float(qq.x << 16),          a0.x);
        a0.y = fmaf(w, __uint_as_float(qq.x & 0xFFFF0000u),  a0.y);
        a0.z = fmaf(w, __uint_as_float(qq.y << 16),          a0.z);
        a0.w = fmaf(w, __uint_as_float(qq.y & 0xFFFF0000u),  a0.w);
        a1.x = fmaf(w, __uint_as_float(qq.z << 16),          a1.x);
        a1.y = fmaf(w, __uint_as_float(qq.z & 0xFFFF0000u),  a1.y);
        a1.z = fmaf(w, __uint_as_float(qq.w << 16),          a1.z);
        a1.w = fmaf(w, __uint_as_float(qq.w & 0xFFFF0000u),  a1.w);
    }
    float syn = butterfly8(a0, a1, sub);
    syn += __shfl_xor(syn, 8);               // merge the two 8-lane groups
    if (s16 < 8) {
        size_t idx = (size_t)n * 8 + sub;
        float vn = v_w[idx] * cf.x + syn * cf.y + cF[idx];
        v_w[idx] = vn;
        r_next[idx] = (unsigned short)f2bf_rne(fmaxf(vn, 0.f));
    }
}

__global__ void k_out(const float* __restrict__ v_w, float* __restrict__ out, int N) {
    int t = blockIdx.x * BLK + threadIdx.x;
    if (t >= NBATCH * N) return;
    int b = t / N;
    int n = t - b * N;
    out[t] = v_w[(size_t)n * 8 + b];
}

static inline size_t align16(size_t x) { return (x + 15) & ~(size_t)15; }

extern "C" void kernel_launch(void* const* d_in, const int* in_sizes, int n_in,
                              void* d_out, int out_size, void* d_ws, size_t ws_size,
                              hipStream_t stream) {
    const float* tm1_in  = (const float*)d_in[0];
    const float* v_init  = (const float*)d_in[1];
    const float* weights = (const float*)d_in[2];
    const float* bias    = (const float*)d_in[3];
    const float* tau_p   = (const float*)d_in[4];
    const float* se      = (const float*)d_in[5];
    const float* si      = (const float*)d_in[6];
    const int*   srcI    = (const int*)d_in[7];
    const int*   tgtI    = (const int*)d_in[8];
    const int*   type_ids= (const int*)d_in[9];
    const int*   tm1_idx = (const int*)d_in[10];

    const int E  = in_sizes[2];
    const int N  = in_sizes[3];
    const int NT = in_sizes[10];

    char* p = (char*)d_ws;
    size_t off = 0;
    auto take = [&](size_t bytes) { void* r = p + off; off += align16(bytes); return r; };
    int*      offsets = (int*)     take((size_t)(N + 1) * 4);
    int*      cursorD = (int*)     take((size_t)N * 4);
    int*      cursorS = (int*)     take((size_t)N * 4);
    int*      counts  = (int*)     take((size_t)N * 4);
    int*      countS  = (int*)     take((size_t)N * 4);
    int*      dynEnd  = (int*)     take((size_t)N * 4);
    int*      tm1_pos = (int*)     take((size_t)N * 4);
    int*      bsum    = (int*)     take(1024 * 4);
    unsigned char* flagA = (unsigned char*)take((size_t)E);
    unsigned* csr     = (unsigned*)take((size_t)E * 4);
    float4*   coef    = (float4*)  take((size_t)N * 16);
    float*    cF      = (float*)   take((size_t)N * 8 * 4);
    float*    v_w     = (float*)   take((size_t)N * 8 * 4);
    uint4*    r0      = (uint4*)   take((size_t)N * 16);     // bf16 rows
    uint4*    r1      = (uint4*)   take((size_t)N * 16);
    (void)ws_size;

    const int gN  = (N + BLK - 1) / BLK;
    const int gN1 = (N + 1 + BLK - 1) / BLK;
    const int gE  = (E + BLK - 1) / BLK;
    const int gNT = (NT + BLK - 1) / BLK;
    const int g8  = (N * 8 + BLK - 1) / BLK;
    const int g16 = (N * 16 + BLK - 1) / BLK;

    k_zero<<<gN, BLK, 0, stream>>>(counts, countS, tm1_pos, N);
    k_tm1pos<<<gNT, BLK, 0, stream>>>(tm1_idx, tm1_pos, NT);
    k_hist<<<gE, BLK, 0, stream>>>(srcI, tgtI, type_ids, counts, countS, flagA, E);
    k_scan1<<<gN, BLK, 0, stream>>>(counts, offsets, bsum, N);
    k_scan2<<<1, BLK, 0, stream>>>(bsum, gN);
    k_scan3<<<gN1, BLK, 0, stream>>>(bsum, offsets, N, E);
    k_cursors<<<gN, BLK, 0, stream>>>(offsets, countS, cursorD, cursorS, dynEnd, N);
    k_fill<<<gE, BLK, 0, stream>>>(srcI, tgtI, weights, se, si, flagA,
                                   cursorD, cursorS, csr, E);
    k_initv<<<gN, BLK, 0, stream>>>(tm1_in, v_init, tau_p, type_ids, tm1_pos,
                                    v_w, r0, r1, coef, N, NT);
    k_static<<<g8, BLK, 0, stream>>>(offsets, dynEnd, csr, r0, coef, bias, cF, N);

    uint4* rb[2] = { r0, r1 };
    for (int s = 0; s < STEPS; ++s) {
        k_step<<<g16, BLK, 0, stream>>>(offsets, dynEnd, csr, coef, cF, rb[s & 1],
                                        v_w, (unsigned short*)rb[(s + 1) & 1], N);
    }
    k_out<<<g8, BLK, 0, stream>>>(v_w, (float*)d_out, N);
}